// Round 1
// baseline (218.535 us; speedup 1.0000x reference)
//
#include <hip/hip_runtime.h>
#include <hip/hip_bf16.h>

// Problem constants (fixed by the reference)
#define B_   32
#define D_   3584
#define NH_  28
#define NKV_ 4
#define HD_  128
#define SW_  4096
#define GRP_ 7                    // NH/NKV
#define NQKV_ 4608                // (NH+2*NKV)*HD
#define SCALE_ 0.08838834764831845f  // HD^-0.5
#define NKC_ 16                   // split-K chunks for projections
#define KC_  224                  // D_/NKC_
#define NCHUNK_ 8                 // attention s-chunks
#define CHUNK_ 512                // SW_/NCHUNK_

// ---------------------------------------------------------------------------
// Split-K projection: P[kc][32][N] = X[32][3584] @ W[3584][N]  (partial sums)
// Block: 256 thr = 4 waves; wave w owns rows 8w..8w+7 (x reads wave-uniform ->
// scalar loads); lane owns a float2 of columns (coalesced W reads).
// ---------------------------------------------------------------------------
__global__ __launch_bounds__(256) void proj_kernel(const float* __restrict__ X,
                                                   const float* __restrict__ W,
                                                   float* __restrict__ P, int N) {
    const int lane = threadIdx.x & 63;
    const int wv   = __builtin_amdgcn_readfirstlane(threadIdx.x >> 6);
    const int r0   = wv * 8;
    const int c2   = blockIdx.x * 64 + lane;   // float2 column index
    const int k0   = blockIdx.y * KC_;
    const int n2   = N >> 1;
    const float2* __restrict__ W2 = (const float2*)W;

    float2 acc[8];
#pragma unroll
    for (int i = 0; i < 8; ++i) acc[i] = make_float2(0.f, 0.f);

#pragma unroll 4
    for (int k = k0; k < k0 + KC_; ++k) {
        float2 w2 = W2[(size_t)k * n2 + c2];
#pragma unroll
        for (int i = 0; i < 8; ++i) {
            float xr = X[(size_t)(r0 + i) * D_ + k];   // wave-uniform -> s_load
            acc[i].x += xr * w2.x;
            acc[i].y += xr * w2.y;
        }
    }
    float2* P2 = (float2*)P;
#pragma unroll
    for (int i = 0; i < 8; ++i)
        P2[(size_t)(blockIdx.y * 32 + r0 + i) * n2 + c2] = acc[i];
}

// ---------------------------------------------------------------------------
// QKV finish: xqkv[r][c] = sum_kc P + bias, then RoPE on q/k sections
// (rot_mat is block-diagonal 2x2 by construction), q scaled by HD^-0.5.
// One thread per column PAIR.
// ---------------------------------------------------------------------------
__global__ __launch_bounds__(256) void qkv_finish(const float* __restrict__ P,
                                                  const float* __restrict__ bias,
                                                  const float* __restrict__ rot,
                                                  float* __restrict__ xqkv) {
    int t  = blockIdx.x * 256 + threadIdx.x;     // pair id, 32*2304 total
    int r  = t / (NQKV_ / 2);
    int cp = t - r * (NQKV_ / 2);
    int c0 = cp * 2;

    float v0 = bias[c0], v1 = bias[c0 + 1];
#pragma unroll
    for (int kc = 0; kc < NKC_; ++kc) {
        float2 pv = *(const float2*)&P[((size_t)(kc * 32 + r) * NQKV_) + c0];
        v0 += pv.x; v1 += pv.y;
    }
    if (c0 < (NH_ + NKV_) * HD_) {               // q and k sections get RoPE
        int j = (c0 & (HD_ - 1)) >> 1;           // head-local pair index
        float cs = rot[(2 * j) * HD_ + 2 * j];
        float sn = rot[(2 * j) * HD_ + 2 * j + 1];
        float o0 = v0 * cs - v1 * sn;
        float o1 = v0 * sn + v1 * cs;
        if (c0 < NH_ * HD_) { o0 *= SCALE_; o1 *= SCALE_; }   // fold q scale
        v0 = o0; v1 = o1;
    }
    *(float2*)&xqkv[(size_t)r * NQKV_ + c0] = make_float2(v0, v1);
}

// ---------------------------------------------------------------------------
// Flash-decode attention over one (b, kv, s-chunk). Produces unnormalized
// partial ctx[7][128] plus per-head (m, l).
// ---------------------------------------------------------------------------
__global__ __launch_bounds__(256) void attn_kernel(const float* __restrict__ xqkv,
                                                   const float* __restrict__ cache_k,
                                                   const float* __restrict__ cache_v,
                                                   const int* __restrict__ curp,
                                                   float* __restrict__ part_ctx,
                                                   float* __restrict__ part_ml) {
    __shared__ __align__(16) float p[GRP_][CHUNK_];   // logits -> exp weights
    __shared__ float redm[GRP_][4], redl[GRP_][4];

    const int bid  = blockIdx.x;
    const int c    = bid & (NCHUNK_ - 1);
    const int kv   = (bid >> 3) & (NKV_ - 1);
    const int b    = bid >> 5;
    const int tid  = threadIdx.x;
    const int lane = tid & 63;
    const int wv   = tid >> 6;

    const int cur  = curp[0];
    const int slot = cur & (SW_ - 1);
    const int sbase = c * CHUNK_;

    const float* qb   = xqkv + (size_t)b * NQKV_ + kv * (GRP_ * HD_);
    const float4* q4  = (const float4*)qb;
    const float* knew = xqkv + (size_t)b * NQKV_ + NH_ * HD_ + kv * HD_;
    const float* kcb  = cache_k + ((size_t)(b * NKV_ + kv) * SW_) * HD_;

    // ---- Phase 1: QK^T for 2 rows per thread -----------------------------
    const int s0 = sbase + tid, s1 = sbase + 256 + tid;
    const float4* k0p = (const float4*)((s0 == slot) ? knew : kcb + (size_t)s0 * HD_);
    const float4* k1p = (const float4*)((s1 == slot) ? knew : kcb + (size_t)s1 * HD_);

    float a0[GRP_], a1[GRP_];
#pragma unroll
    for (int h = 0; h < GRP_; ++h) { a0[h] = 0.f; a1[h] = 0.f; }

#pragma unroll 4
    for (int dc = 0; dc < HD_ / 4; ++dc) {
        float4 ka = k0p[dc], kb = k1p[dc];
#pragma unroll
        for (int h = 0; h < GRP_; ++h) {
            float4 qv = q4[h * (HD_ / 4) + dc];   // wave-uniform -> scalar path
            a0[h] += qv.x * ka.x + qv.y * ka.y + qv.z * ka.z + qv.w * ka.w;
            a1[h] += qv.x * kb.x + qv.y * kb.y + qv.z * kb.z + qv.w * kb.w;
        }
    }
    const bool vld0 = (s0 <= cur), vld1 = (s1 <= cur);
#pragma unroll
    for (int h = 0; h < GRP_; ++h) {
        if (!vld0) a0[h] = -1e30f;
        if (!vld1) a1[h] = -1e30f;
    }

    // per-head max across block
#pragma unroll
    for (int h = 0; h < GRP_; ++h) {
        float mx = fmaxf(a0[h], a1[h]);
#pragma unroll
        for (int off = 32; off; off >>= 1) mx = fmaxf(mx, __shfl_xor(mx, off));
        if (lane == 0) redm[h][wv] = mx;
    }
    __syncthreads();

    float mh[GRP_];
#pragma unroll
    for (int h = 0; h < GRP_; ++h) {
        mh[h] = fmaxf(fmaxf(redm[h][0], redm[h][1]), fmaxf(redm[h][2], redm[h][3]));
        float e0 = __expf(a0[h] - mh[h]);
        float e1 = __expf(a1[h] - mh[h]);
        p[h][tid]       = e0;
        p[h][tid + 256] = e1;
        float ls = e0 + e1;
#pragma unroll
        for (int off = 32; off; off >>= 1) ls += __shfl_xor(ls, off);
        if (lane == 0) redl[h][wv] = ls;
    }
    __syncthreads();

    // ---- Phase 2: P @ V. Wave w owns contiguous s in [128w, 128w+128). ----
    const float2* vcb   = (const float2*)(cache_v + ((size_t)(b * NKV_ + kv) * SW_) * HD_);
    const float2* vnew2 = (const float2*)(xqkv + (size_t)b * NQKV_ + (NH_ + NKV_) * HD_ + kv * HD_);

    float2 acc2[GRP_];
#pragma unroll
    for (int h = 0; h < GRP_; ++h) acc2[h] = make_float2(0.f, 0.f);

    const int sA = wv * 128;
#pragma unroll 4
    for (int s = sA; s < sA + 128; s += 2) {
        const int sg0 = sbase + s, sg1 = sg0 + 1;
        const float2* vp0 = (sg0 == slot) ? vnew2 : vcb + (size_t)sg0 * (HD_ / 2);
        const float2* vp1 = (sg1 == slot) ? vnew2 : vcb + (size_t)sg1 * (HD_ / 2);
        float2 vv0 = vp0[lane], vv1 = vp1[lane];
#pragma unroll
        for (int h = 0; h < GRP_; ++h) {
            float2 pp = *(const float2*)&p[h][s];   // broadcast read
            acc2[h].x += pp.x * vv0.x + pp.y * vv1.x;
            acc2[h].y += pp.x * vv0.y + pp.y * vv1.y;
        }
    }
    __syncthreads();                 // all p reads done; reuse p as ctx buffer

    float2* ctxl = (float2*)&p[0][0];        // [4][GRP_*64] float2
#pragma unroll
    for (int h = 0; h < GRP_; ++h)
        ctxl[wv * (GRP_ * 64) + h * 64 + lane] = acc2[h];
    __syncthreads();

    const float* ctxf = (const float*)ctxl;
    for (int i = tid; i < GRP_ * HD_; i += 256) {
        float s = ctxf[i] + ctxf[896 + i] + ctxf[1792 + i] + ctxf[2688 + i];
        part_ctx[(size_t)bid * (GRP_ * HD_) + i] = s;
    }
    if (tid < GRP_) {
        part_ml[bid * 14 + tid]     = fmaxf(fmaxf(redm[tid][0], redm[tid][1]),
                                            fmaxf(redm[tid][2], redm[tid][3]));
        part_ml[bid * 14 + 7 + tid] = redl[tid][0] + redl[tid][1] + redl[tid][2] + redl[tid][3];
    }
}

// ---------------------------------------------------------------------------
// Combine the 8 chunk partials per (b, kv): flash-decoding rescale + normalize.
// ---------------------------------------------------------------------------
__global__ __launch_bounds__(256) void combine_kernel(const float* __restrict__ part_ctx,
                                                      const float* __restrict__ part_ml,
                                                      float* __restrict__ ctx) {
    const int g   = blockIdx.x;           // b*NKV + kv
    const int tid = threadIdx.x;
    __shared__ float fac[NCHUNK_][GRP_];

    if (tid < GRP_) {
        float M = part_ml[(g * NCHUNK_) * 14 + tid];
#pragma unroll
        for (int cc = 1; cc < NCHUNK_; ++cc)
            M = fmaxf(M, part_ml[(g * NCHUNK_ + cc) * 14 + tid]);
        float L = 0.f;
        float e[NCHUNK_];
#pragma unroll
        for (int cc = 0; cc < NCHUNK_; ++cc) {
            e[cc] = __expf(part_ml[(g * NCHUNK_ + cc) * 14 + tid] - M);
            L += part_ml[(g * NCHUNK_ + cc) * 14 + 7 + tid] * e[cc];
        }
        float inv = 1.f / L;
#pragma unroll
        for (int cc = 0; cc < NCHUNK_; ++cc) fac[cc][tid] = e[cc] * inv;
    }
    __syncthreads();

    const int b = g >> 2, kv = g & 3;
    for (int i = tid; i < GRP_ * HD_; i += 256) {
        int h = i >> 7;
        float s = 0.f;
#pragma unroll
        for (int cc = 0; cc < NCHUNK_; ++cc)
            s += part_ctx[(size_t)(g * NCHUNK_ + cc) * (GRP_ * HD_) + i] * fac[cc][h];
        ctx[(size_t)b * D_ + kv * (GRP_ * HD_) + i] = s;
    }
}

// ---------------------------------------------------------------------------
// Final reduce of O-projection split-K partials into d_out.
// ---------------------------------------------------------------------------
__global__ __launch_bounds__(256) void out_finish(const float* __restrict__ P,
                                                  float* __restrict__ out) {
    int t = blockIdx.x * 256 + threadIdx.x;   // < 32*3584
    float s = 0.f;
#pragma unroll
    for (int kc = 0; kc < NKC_; ++kc) s += P[(size_t)kc * (32 * D_) + t];
    out[t] = s;
}

// ---------------------------------------------------------------------------
extern "C" void kernel_launch(void* const* d_in, const int* in_sizes, int n_in,
                              void* d_out, int out_size, void* d_ws, size_t ws_size,
                              hipStream_t stream) {
    const float* x    = (const float*)d_in[0];
    const float* wqkv = (const float*)d_in[1];
    const float* bias = (const float*)d_in[2];
    const float* wo   = (const float*)d_in[3];
    const float* rot  = (const float*)d_in[4];
    const float* ck   = (const float*)d_in[5];
    const float* cv   = (const float*)d_in[6];
    const int*   cur  = (const int*)d_in[7];
    float* out = (float*)d_out;
    float* ws  = (float*)d_ws;

    // workspace layout (floats)
    float* partials = ws;                                   // 16*32*4608 = 2,359,296
    float* xqkv     = partials + (size_t)NKC_ * 32 * NQKV_; //   147,456
    float* pctx     = xqkv + (size_t)B_ * NQKV_;            //   917,504
    float* pml      = pctx + (size_t)B_ * NKV_ * NCHUNK_ * GRP_ * HD_; // 14,336
    float* ctx      = pml  + (size_t)B_ * NKV_ * NCHUNK_ * 14;         // 114,688

    // 1) QKV projection (split-K partials)
    proj_kernel<<<dim3(NQKV_ / 128, NKC_), 256, 0, stream>>>(x, wqkv, partials, NQKV_);
    // 2) bias + RoPE + q-scale
    qkv_finish<<<(B_ * NQKV_ / 2) / 256, 256, 0, stream>>>(partials, bias, rot, xqkv);
    // 3) flash-decode attention over (b, kv, chunk)
    attn_kernel<<<B_ * NKV_ * NCHUNK_, 256, 0, stream>>>(xqkv, ck, cv, cur, pctx, pml);
    // 4) combine chunks
    combine_kernel<<<B_ * NKV_, 256, 0, stream>>>(pctx, pml, ctx);
    // 5) output projection (split-K partials, reuse buffer)
    proj_kernel<<<dim3(D_ / 128, NKC_), 256, 0, stream>>>(ctx, wo, partials, D_);
    // 6) reduce into d_out
    out_finish<<<(B_ * D_) / 256, 256, 0, stream>>>(partials, out);
}

// Round 2
// 197.646 us; speedup vs baseline: 1.1057x; 1.1057x over previous
//
#include <hip/hip_runtime.h>
#include <hip/hip_bf16.h>

// Problem constants (fixed by the reference)
#define B_   32
#define D_   3584
#define NH_  28
#define NKV_ 4
#define HD_  128
#define SW_  4096
#define GRP_ 7                    // NH/NKV
#define NQKV_ 4608                // (NH+2*NKV)*HD
#define SCALE_ 0.08838834764831845f  // HD^-0.5
#define NKC_ 16                   // split-K chunks for projections
#define KC_  224                  // D_/NKC_
#define NCHUNK_ 16                // attention s-chunks (grid = 32*4*16 = 2048 blocks = 8/CU)
#define CHUNK_ 256                // SW_/NCHUNK_

// ---------------------------------------------------------------------------
// Split-K projection: P[kc][32][N] = X[32][3584] @ W[3584][N]  (partial sums)
// ---------------------------------------------------------------------------
__global__ __launch_bounds__(256) void proj_kernel(const float* __restrict__ X,
                                                   const float* __restrict__ W,
                                                   float* __restrict__ P, int N) {
    const int lane = threadIdx.x & 63;
    const int wv   = __builtin_amdgcn_readfirstlane(threadIdx.x >> 6);
    const int r0   = wv * 8;
    const int c2   = blockIdx.x * 64 + lane;   // float2 column index
    const int k0   = blockIdx.y * KC_;
    const int n2   = N >> 1;
    const float2* __restrict__ W2 = (const float2*)W;

    float2 acc[8];
#pragma unroll
    for (int i = 0; i < 8; ++i) acc[i] = make_float2(0.f, 0.f);

#pragma unroll 4
    for (int k = k0; k < k0 + KC_; ++k) {
        float2 w2 = W2[(size_t)k * n2 + c2];
#pragma unroll
        for (int i = 0; i < 8; ++i) {
            float xr = X[(size_t)(r0 + i) * D_ + k];   // wave-uniform -> s_load
            acc[i].x += xr * w2.x;
            acc[i].y += xr * w2.y;
        }
    }
    float2* P2 = (float2*)P;
#pragma unroll
    for (int i = 0; i < 8; ++i)
        P2[(size_t)(blockIdx.y * 32 + r0 + i) * n2 + c2] = acc[i];
}

// ---------------------------------------------------------------------------
// QKV finish: sum split-K partials + bias, RoPE (block-diag 2x2), q*scale.
// ---------------------------------------------------------------------------
__global__ __launch_bounds__(256) void qkv_finish(const float* __restrict__ P,
                                                  const float* __restrict__ bias,
                                                  const float* __restrict__ rot,
                                                  float* __restrict__ xqkv) {
    int t  = blockIdx.x * 256 + threadIdx.x;     // pair id, 32*2304 total
    int r  = t / (NQKV_ / 2);
    int cp = t - r * (NQKV_ / 2);
    int c0 = cp * 2;

    float v0 = bias[c0], v1 = bias[c0 + 1];
#pragma unroll
    for (int kc = 0; kc < NKC_; ++kc) {
        float2 pv = *(const float2*)&P[((size_t)(kc * 32 + r) * NQKV_) + c0];
        v0 += pv.x; v1 += pv.y;
    }
    if (c0 < (NH_ + NKV_) * HD_) {               // q and k sections get RoPE
        int j = (c0 & (HD_ - 1)) >> 1;           // head-local pair index
        float cs = rot[(2 * j) * HD_ + 2 * j];
        float sn = rot[(2 * j) * HD_ + 2 * j + 1];
        float o0 = v0 * cs - v1 * sn;
        float o1 = v0 * sn + v1 * cs;
        if (c0 < NH_ * HD_) { o0 *= SCALE_; o1 *= SCALE_; }   // fold q scale
        v0 = o0; v1 = o1;
    }
    *(float2*)&xqkv[(size_t)r * NQKV_ + c0] = make_float2(v0, v1);
}

// ---------------------------------------------------------------------------
// Flash-decode attention over one (b, kv, s-chunk of 256).
// Phase 1: one K-row per thread. Phase 2: wave w owns rows [64w, 64w+64).
// ---------------------------------------------------------------------------
__global__ __launch_bounds__(256) void attn_kernel(const float* __restrict__ xqkv,
                                                   const float* __restrict__ cache_k,
                                                   const float* __restrict__ cache_v,
                                                   const int* __restrict__ curp,
                                                   float* __restrict__ part_ctx,
                                                   float* __restrict__ part_ml) {
    __shared__ __align__(16) float p[GRP_][CHUNK_];   // exp weights (7 KB)
    __shared__ float redm[GRP_][4], redl[GRP_][4];

    const int bid  = blockIdx.x;
    const int c    = bid & (NCHUNK_ - 1);
    const int kv   = (bid >> 4) & (NKV_ - 1);
    const int b    = bid >> 6;
    const int tid  = threadIdx.x;
    const int lane = tid & 63;
    const int wv   = tid >> 6;

    const int cur   = curp[0];
    const int slot  = cur & (SW_ - 1);
    const int sbase = c * CHUNK_;

    const float* qb   = xqkv + (size_t)b * NQKV_ + kv * (GRP_ * HD_);
    const float4* q4  = (const float4*)qb;
    const float* knew = xqkv + (size_t)b * NQKV_ + NH_ * HD_ + kv * HD_;
    const float* kcb  = cache_k + ((size_t)(b * NKV_ + kv) * SW_) * HD_;

    // ---- Phase 1: QK^T, one row per thread -------------------------------
    const int s0 = sbase + tid;
    const float4* k0p = (const float4*)((s0 == slot) ? knew : kcb + (size_t)s0 * HD_);

    float a0[GRP_];
#pragma unroll
    for (int h = 0; h < GRP_; ++h) a0[h] = 0.f;

#pragma unroll 4
    for (int dc = 0; dc < HD_ / 4; ++dc) {
        float4 ka = k0p[dc];
#pragma unroll
        for (int h = 0; h < GRP_; ++h) {
            float4 qv = q4[h * (HD_ / 4) + dc];   // block-uniform -> L1 broadcast
            a0[h] += qv.x * ka.x + qv.y * ka.y + qv.z * ka.z + qv.w * ka.w;
        }
    }
    const bool vld0 = (s0 <= cur);
#pragma unroll
    for (int h = 0; h < GRP_; ++h)
        if (!vld0) a0[h] = -1e30f;

    // per-head max across block
#pragma unroll
    for (int h = 0; h < GRP_; ++h) {
        float mx = a0[h];
#pragma unroll
        for (int off = 32; off; off >>= 1) mx = fmaxf(mx, __shfl_xor(mx, off));
        if (lane == 0) redm[h][wv] = mx;
    }
    __syncthreads();

#pragma unroll
    for (int h = 0; h < GRP_; ++h) {
        float mh = fmaxf(fmaxf(redm[h][0], redm[h][1]), fmaxf(redm[h][2], redm[h][3]));
        float e0 = __expf(a0[h] - mh);
        p[h][tid] = e0;
        float ls = e0;
#pragma unroll
        for (int off = 32; off; off >>= 1) ls += __shfl_xor(ls, off);
        if (lane == 0) redl[h][wv] = ls;
    }
    __syncthreads();

    // ---- Phase 2: P @ V. Wave w owns contiguous s in [64w, 64w+64). -------
    const float2* vcb   = (const float2*)(cache_v + ((size_t)(b * NKV_ + kv) * SW_) * HD_);
    const float2* vnew2 = (const float2*)(xqkv + (size_t)b * NQKV_ + (NH_ + NKV_) * HD_ + kv * HD_);

    float2 acc2[GRP_];
#pragma unroll
    for (int h = 0; h < GRP_; ++h) acc2[h] = make_float2(0.f, 0.f);

    const int sA = wv * 64;
#pragma unroll 4
    for (int s = sA; s < sA + 64; s += 2) {
        const int sg0 = sbase + s, sg1 = sg0 + 1;
        const float2* vp0 = (sg0 == slot) ? vnew2 : vcb + (size_t)sg0 * (HD_ / 2);
        const float2* vp1 = (sg1 == slot) ? vnew2 : vcb + (size_t)sg1 * (HD_ / 2);
        float2 vv0 = vp0[lane], vv1 = vp1[lane];
#pragma unroll
        for (int h = 0; h < GRP_; ++h) {
            float2 pp = *(const float2*)&p[h][s];   // broadcast read
            acc2[h].x += pp.x * vv0.x + pp.y * vv1.x;
            acc2[h].y += pp.x * vv0.y + pp.y * vv1.y;
        }
    }
    __syncthreads();                 // all p reads done; reuse p as ctx buffer

    float2* ctxl = (float2*)&p[0][0];        // [4][GRP_*64] float2 = 28 KB? no: 4*448*8 = 14336 B > 7168!
    // NOTE: p is only 7168 B; we need 14336 B for 4 waves * 7 heads * 64 lanes * float2.
    // Use a dedicated buffer instead (declared below).
    __shared__ __align__(16) float2 ctxbuf[4][GRP_ * 64];   // 14336 B
#pragma unroll
    for (int h = 0; h < GRP_; ++h)
        ctxbuf[wv][h * 64 + lane] = acc2[h];
    __syncthreads();

    const float* c0f = (const float*)&ctxbuf[0][0];
    const float* c1f = (const float*)&ctxbuf[1][0];
    const float* c2f = (const float*)&ctxbuf[2][0];
    const float* c3f = (const float*)&ctxbuf[3][0];
    for (int i = tid; i < GRP_ * HD_; i += 256) {
        float s = c0f[i] + c1f[i] + c2f[i] + c3f[i];
        part_ctx[(size_t)bid * (GRP_ * HD_) + i] = s;
    }
    if (tid < GRP_) {
        part_ml[bid * 14 + tid]     = fmaxf(fmaxf(redm[tid][0], redm[tid][1]),
                                            fmaxf(redm[tid][2], redm[tid][3]));
        part_ml[bid * 14 + 7 + tid] = redl[tid][0] + redl[tid][1] + redl[tid][2] + redl[tid][3];
    }
}

// ---------------------------------------------------------------------------
// Combine the 16 chunk partials per (b, kv): flash-decoding rescale+normalize.
// ---------------------------------------------------------------------------
__global__ __launch_bounds__(256) void combine_kernel(const float* __restrict__ part_ctx,
                                                      const float* __restrict__ part_ml,
                                                      float* __restrict__ ctx) {
    const int g   = blockIdx.x;           // b*NKV + kv
    const int tid = threadIdx.x;
    __shared__ float fac[NCHUNK_][GRP_];

    if (tid < GRP_) {
        float M = part_ml[(g * NCHUNK_) * 14 + tid];
#pragma unroll
        for (int cc = 1; cc < NCHUNK_; ++cc)
            M = fmaxf(M, part_ml[(g * NCHUNK_ + cc) * 14 + tid]);
        float L = 0.f;
        float e[NCHUNK_];
#pragma unroll
        for (int cc = 0; cc < NCHUNK_; ++cc) {
            e[cc] = __expf(part_ml[(g * NCHUNK_ + cc) * 14 + tid] - M);
            L += part_ml[(g * NCHUNK_ + cc) * 14 + 7 + tid] * e[cc];
        }
        float inv = 1.f / L;
#pragma unroll
        for (int cc = 0; cc < NCHUNK_; ++cc) fac[cc][tid] = e[cc] * inv;
    }
    __syncthreads();

    const int b = g >> 2, kv = g & 3;
    for (int i = tid; i < GRP_ * HD_; i += 256) {
        int h = i >> 7;
        float s = 0.f;
#pragma unroll
        for (int cc = 0; cc < NCHUNK_; ++cc)
            s += part_ctx[(size_t)(g * NCHUNK_ + cc) * (GRP_ * HD_) + i] * fac[cc][h];
        ctx[(size_t)b * D_ + kv * (GRP_ * HD_) + i] = s;
    }
}

// ---------------------------------------------------------------------------
// Final reduce of O-projection split-K partials into d_out.
// ---------------------------------------------------------------------------
__global__ __launch_bounds__(256) void out_finish(const float* __restrict__ P,
                                                  float* __restrict__ out) {
    int t = blockIdx.x * 256 + threadIdx.x;   // < 32*3584
    float s = 0.f;
#pragma unroll
    for (int kc = 0; kc < NKC_; ++kc) s += P[(size_t)kc * (32 * D_) + t];
    out[t] = s;
}

// ---------------------------------------------------------------------------
extern "C" void kernel_launch(void* const* d_in, const int* in_sizes, int n_in,
                              void* d_out, int out_size, void* d_ws, size_t ws_size,
                              hipStream_t stream) {
    const float* x    = (const float*)d_in[0];
    const float* wqkv = (const float*)d_in[1];
    const float* bias = (const float*)d_in[2];
    const float* wo   = (const float*)d_in[3];
    const float* rot  = (const float*)d_in[4];
    const float* ck   = (const float*)d_in[5];
    const float* cv   = (const float*)d_in[6];
    const int*   cur  = (const int*)d_in[7];
    float* out = (float*)d_out;
    float* ws  = (float*)d_ws;

    // workspace layout (floats). pctx ALIASES partials: partials is dead after
    // qkv_finish and is rewritten only by the later O-projection, which runs
    // after combine_kernel has consumed pctx. 2,359,296 > 1,835,008 so it fits.
    float* partials = ws;                                   // 16*32*4608 = 2,359,296 f
    float* pctx     = partials;                             // 32*4*16*896 = 1,835,008 f (alias)
    float* xqkv     = partials + (size_t)NKC_ * 32 * NQKV_; //   147,456 f
    float* pml      = xqkv + (size_t)B_ * NQKV_;            //    28,672 f
    float* ctx      = pml  + (size_t)B_ * NKV_ * NCHUNK_ * 14; // 114,688 f

    // 1) QKV projection (split-K partials)
    proj_kernel<<<dim3(NQKV_ / 128, NKC_), 256, 0, stream>>>(x, wqkv, partials, NQKV_);
    // 2) bias + RoPE + q-scale
    qkv_finish<<<(B_ * NQKV_ / 2) / 256, 256, 0, stream>>>(partials, bias, rot, xqkv);
    // 3) flash-decode attention over (b, kv, chunk)
    attn_kernel<<<B_ * NKV_ * NCHUNK_, 256, 0, stream>>>(xqkv, ck, cv, cur, pctx, pml);
    // 4) combine chunks
    combine_kernel<<<B_ * NKV_, 256, 0, stream>>>(pctx, pml, ctx);
    // 5) output projection (split-K partials, reuse buffer)
    proj_kernel<<<dim3(D_ / 128, NKC_), 256, 0, stream>>>(ctx, wo, partials, D_);
    // 6) reduce into d_out
    out_finish<<<(B_ * D_) / 256, 256, 0, stream>>>(partials, out);
}